// Round 3
// 14694.514 us; speedup vs baseline: 1.1204x; 1.1204x over previous
//
#include <hip/hip_runtime.h>
#include <string.h>

#define T_STEPS 256
#define B_SZ    128
#define S_SZ    512
#define D_SZ    256
#define NG      1024   // 4*HID

// ---- static device scratch (graph-capture safe, ws_size-independent) ----
__device__ float g_proj[(size_t)B_SZ * S_SZ * 256];     // 64 MiB, [b][s][d] fp32
__device__ float g_E[(size_t)T_STEPS * B_SZ * 1024];    // 128 MiB, [t][b][j]: emb@W_ih_emb.T
__device__ float g_WihT[512 * 1024];                    // [k][j] fp32 (k<256: emb rows, k>=256: ctx rows)
__device__ float g_WhhT[256 * 1024];                    // [k][j] fp32
__device__ float g_WhT [256 * 256];                     // [k][d] fp32
__device__ float g_WmT [256 * 256];                     // [e][d] fp32
__device__ float g_bias[1024];

__device__ __forceinline__ float tanh_f(float x){
    float r = __expf(2.f * x);          // exp(+inf)=inf, exp(-inf)=0 -> no NaN
    return 1.f - 2.f / (r + 1.f);
}
__device__ __forceinline__ float sigm_f(float x){
    return 1.f / (1.f + __expf(-x));
}

// ---- packing kernels (fp32 -> fp32 transposes) ----

// W_attn: [256][512] -> W_hT [k=256][d=256], W_mT [e=256][d=256]
__global__ void pack_attn(const float* __restrict__ W_attn){
    int id = blockIdx.x * 256 + threadIdx.x;   // 65536
    int d = id >> 8, k = id & 255;
    g_WhT[k * 256 + d] = W_attn[d * 512 + k];
    g_WmT[k * 256 + d] = W_attn[d * 512 + 256 + k];
}

// W_ih [1024][512] -> W_ihT [512][1024]
__global__ void pack_wih(const float* __restrict__ W){
    int id = blockIdx.x * 256 + threadIdx.x;   // 524288
    int j = id >> 9, k = id & 511;
    g_WihT[k * 1024 + j] = W[id];
}
// W_hh [1024][256] -> W_hhT [256][1024]
__global__ void pack_whh(const float* __restrict__ W){
    int id = blockIdx.x * 256 + threadIdx.x;   // 262144
    int j = id >> 8, k = id & 255;
    g_WhhT[k * 1024 + j] = W[id];
}
__global__ void pack_bias(const float* __restrict__ bih, const float* __restrict__ bhh){
    int j = blockIdx.x * 256 + threadIdx.x;    // 1024
    g_bias[j] = bih[j] + bhh[j];
}

// g_proj [b][s][d] = memory[s][b][:] @ W_mT[e][d] + b_attn   (all fp32)
#define PBM 64
#define PBN 64
#define PBK 32
__global__ __launch_bounds__(256) void mem_proj_gemm(
        const float* __restrict__ memory,     // [S][B][256] fp32
        const float* __restrict__ b_attn){
    __shared__ float As[PBK][PBM + 1];
    __shared__ float Bs[PBK][PBN + 1];
    int tid = threadIdx.x;
    int tm = tid >> 4, tn = tid & 15;
    int row0 = blockIdx.x * PBM;             // row r = b*512 + s
    int col0 = blockIdx.y * PBN;
    float acc[4][4] = {};
    for (int k0 = 0; k0 < 256; k0 += PBK){
        int m = tid >> 2, kq = tid & 3;
        int r  = row0 + m;
        int bb = r >> 9, ss = r & 511;
        const float* ap = memory + ((size_t)ss * B_SZ + bb) * 256 + k0 + kq * 8;
        #pragma unroll
        for (int i = 0; i < 8; ++i) As[kq * 8 + i][m] = ap[i];
        int kk = tid >> 3, dq = tid & 7;
        const float* bp = g_WmT + (size_t)(k0 + kk) * 256 + col0 + dq * 8;
        #pragma unroll
        for (int i = 0; i < 8; ++i) Bs[kk][dq * 8 + i] = bp[i];
        __syncthreads();
        #pragma unroll
        for (int k2 = 0; k2 < PBK; ++k2){
            float a[4], bb2[4];
            #pragma unroll
            for (int i = 0; i < 4; ++i) a[i]   = As[k2][tm * 4 + i];
            #pragma unroll
            for (int i = 0; i < 4; ++i) bb2[i] = Bs[k2][tn * 4 + i];
            #pragma unroll
            for (int i = 0; i < 4; ++i)
                #pragma unroll
                for (int j = 0; j < 4; ++j) acc[i][j] += a[i] * bb2[j];
        }
        __syncthreads();
    }
    #pragma unroll
    for (int i = 0; i < 4; ++i){
        int r = row0 + tm * 4 + i;
        float* pp = g_proj + (size_t)r * 256 + col0 + tn * 4;
        #pragma unroll
        for (int j = 0; j < 4; ++j)
            pp[j] = acc[i][j] + b_attn[col0 + tn * 4 + j];
    }
}

// g_E [r=t*B+b][j] = tgt[r][:256] @ g_WihT[k<256][j]   (no bias; added in decode)
__global__ __launch_bounds__(256) void emb_gemm(
        const float* __restrict__ tgt){       // [T][B][256] fp32, rows contiguous
    __shared__ float As[PBK][PBM + 1];
    __shared__ float Bs[PBK][PBN + 1];
    int tid = threadIdx.x;
    int tm = tid >> 4, tn = tid & 15;
    int row0 = blockIdx.x * PBM;             // 512 blocks x 64 rows = 32768
    int col0 = blockIdx.y * PBN;             // 16 blocks x 64 cols = 1024
    float acc[4][4] = {};
    for (int k0 = 0; k0 < 256; k0 += PBK){
        int m = tid >> 2, kq = tid & 3;
        const float* ap = tgt + (size_t)(row0 + m) * 256 + k0 + kq * 8;
        #pragma unroll
        for (int i = 0; i < 8; ++i) As[kq * 8 + i][m] = ap[i];
        int kk = tid >> 3, dq = tid & 7;
        const float* bp = g_WihT + (size_t)(k0 + kk) * 1024 + col0 + dq * 8;
        #pragma unroll
        for (int i = 0; i < 8; ++i) Bs[kk][dq * 8 + i] = bp[i];
        __syncthreads();
        #pragma unroll
        for (int k2 = 0; k2 < PBK; ++k2){
            float a[4], bb2[4];
            #pragma unroll
            for (int i = 0; i < 4; ++i) a[i]   = As[k2][tm * 4 + i];
            #pragma unroll
            for (int i = 0; i < 4; ++i) bb2[i] = Bs[k2][tn * 4 + i];
            #pragma unroll
            for (int i = 0; i < 4; ++i)
                #pragma unroll
                for (int j = 0; j < 4; ++j) acc[i][j] += a[i] * bb2[j];
        }
        __syncthreads();
    }
    #pragma unroll
    for (int i = 0; i < 4; ++i){
        int r = row0 + tm * 4 + i;
        float* pp = g_E + (size_t)r * 1024 + col0 + tn * 4;
        #pragma unroll
        for (int j = 0; j < 4; ++j)
            pp[j] = acc[i][j];
    }
}

// ---- main persistent scan: one block per batch element, 1024 threads ----
__global__ __launch_bounds__(1024) void decode_scan(
        const float* __restrict__ memory,    // [S][B][256] fp32
        float* __restrict__ out)             // [T][B][256] fp32
{
    const int b    = blockIdx.x;
    const int tid  = threadIdx.x;
    const int lane = tid & 63;
    const int wave = tid >> 6;          // 16 waves

    __shared__ __align__(16) float h_s[256];
    __shared__ __align__(16) float c_s[256];
    __shared__ __align__(16) float hWh_part[4][256];
    __shared__ __align__(16) float hWh[256];
    __shared__ __align__(16) float e_s[512];
    __shared__ __align__(16) float attn[512];
    __shared__ __align__(16) float ctx_part[16][256];
    __shared__ __align__(16) float ctx_s[256];
    __shared__ __align__(16) float g_part[4][1024];
    __shared__ __align__(16) float gates[1024];

    if (tid < 256){
        h_s[tid] = 0.f; c_s[tid] = 0.f;
        out[(size_t)b * 256 + tid] = 0.f;          // out[0] = zeros
    }
    __syncthreads();

    const float* projb = g_proj + (size_t)b * S_SZ * 256;
    const float* memb  = memory + (size_t)b * 256;

    for (int t = 1; t < T_STEPS; ++t){
        // ---- phase 1: hWh[d] = sum_k h[k] * W_h[d][k] ----
        {
            int d = tid & 255, kq = tid >> 8;   // kq in 0..3, 64 k's each
            float acc = 0.f;
            const float* wp = g_WhT + (size_t)(kq * 64) * 256 + d;
            #pragma unroll 8
            for (int k = 0; k < 64; ++k)
                acc += h_s[kq * 64 + k] * wp[(size_t)k * 256];
            hWh_part[kq][d] = acc;
        }
        __syncthreads();
        if (tid < 256)
            hWh[tid] = hWh_part[0][tid] + hWh_part[1][tid] + hWh_part[2][tid] + hWh_part[3][tid];
        __syncthreads();

        // ---- phase 2: e[s] = sum_d tanh(proj[s][d] + hWh[d]) ----
        {
            float4 hv = ((const float4*)hWh)[lane];
            for (int i = 0; i < 32; ++i){
                int s = wave * 32 + i;
                float4 p = ((const float4*)(projb + (size_t)s * 256))[lane];
                float v = tanh_f(p.x + hv.x) + tanh_f(p.y + hv.y)
                        + tanh_f(p.z + hv.z) + tanh_f(p.w + hv.w);
                #pragma unroll
                for (int m = 32; m; m >>= 1) v += __shfl_xor(v, m, 64);
                if (lane == 0) e_s[s] = v;
            }
        }
        __syncthreads();

        // ---- phase 3: softmax over s (wave 0 only) ----
        if (wave == 0){
            float v[8]; float mx = -1e30f;
            #pragma unroll
            for (int i = 0; i < 8; ++i){ v[i] = e_s[lane + 64 * i]; mx = fmaxf(mx, v[i]); }
            #pragma unroll
            for (int m = 32; m; m >>= 1) mx = fmaxf(mx, __shfl_xor(mx, m, 64));
            float zs = 0.f;
            #pragma unroll
            for (int i = 0; i < 8; ++i){ v[i] = __expf(v[i] - mx); zs += v[i]; }
            #pragma unroll
            for (int m = 32; m; m >>= 1) zs += __shfl_xor(zs, m, 64);
            float inv = 1.f / zs;
            #pragma unroll
            for (int i = 0; i < 8; ++i) attn[lane + 64 * i] = v[i] * inv;
        }
        __syncthreads();

        // ---- phase 4: ctx[e] = sum_s attn[s]*mem[s][e] ----
        {
            int e4 = tid & 63, sq = tid >> 6;   // 16 s-groups x 32 s
            float a0=0.f, a1=0.f, a2=0.f, a3=0.f;
            // memory[s][b][e]: row stride B*256 = 32768 floats
            const float* mp = memb + (size_t)(sq * 32) * 32768 + 4 * e4;
            #pragma unroll 4
            for (int s = 0; s < 32; ++s){
                float av = attn[sq * 32 + s];
                float4 w = *(const float4*)(mp + (size_t)s * 32768);
                a0 += av * w.x; a1 += av * w.y;
                a2 += av * w.z; a3 += av * w.w;
            }
            float4 r; r.x=a0; r.y=a1; r.z=a2; r.w=a3;
            ((float4*)ctx_part[sq])[e4] = r;
        }
        __syncthreads();
        if (tid < 256){
            float s = 0.f;
            #pragma unroll
            for (int g = 0; g < 16; ++g) s += ctx_part[g][tid];
            ctx_s[tid] = s;
        }
        __syncthreads();

        // ---- phase 5: gates[j] = ctx@Wc.T + h@W_hh.T + E[t,b,:] + bias ----
        {
            int jq = tid & 255, kh = tid >> 8;  // 4 j's per thread, kh in 0..3
            float a0=0.f, a1=0.f, a2=0.f, a3=0.f;
            const float* src;
            const float* wp;
            if (kh < 2){
                // ctx part: W_ihT rows 256..511
                src = ctx_s + kh * 128;
                wp  = g_WihT + (size_t)(256 + kh * 128) * 1024 + 4 * jq;
            } else {
                // h part: W_hhT rows 0..255
                src = h_s + (kh - 2) * 128;
                wp  = g_WhhT + (size_t)((kh - 2) * 128) * 1024 + 4 * jq;
            }
            #pragma unroll 4
            for (int k = 0; k < 128; ++k){
                float xv = src[k];
                float4 w = *(const float4*)(wp + (size_t)k * 1024);
                a0 += xv * w.x; a1 += xv * w.y;
                a2 += xv * w.z; a3 += xv * w.w;
            }
            float4 r; r.x=a0; r.y=a1; r.z=a2; r.w=a3;
            ((float4*)g_part[kh])[jq] = r;
        }
        __syncthreads();
        {
            const float* Erow = g_E + ((size_t)t * B_SZ + b) * 1024;
            gates[tid] = g_part[0][tid] + g_part[1][tid] + g_part[2][tid]
                       + g_part[3][tid] + Erow[tid] + g_bias[tid];
        }
        __syncthreads();

        // ---- phase 6: LSTM cell, write h ----
        if (tid < 256){
            float ig = sigm_f(gates[tid]);
            float fg = sigm_f(gates[256 + tid]);
            float gg = tanh_f(gates[512 + tid]);
            float og = sigm_f(gates[768 + tid]);
            float cn = fg * c_s[tid] + ig * gg;
            float hn = og * tanh_f(cn);
            c_s[tid] = cn; h_s[tid] = hn;
            out[((size_t)t * B_SZ + b) * 256 + tid] = hn;
        }
        __syncthreads();
    }
}

extern "C" void kernel_launch(void* const* d_in, const int* in_sizes, int n_in,
                              void* d_out, int out_size, void* d_ws, size_t ws_size,
                              hipStream_t stream){
    const float* tgt    = (const float*)d_in[0];
    const float* memory = (const float*)d_in[1];
    const float* W_attn = (const float*)d_in[2];
    const float* b_attn = (const float*)d_in[3];
    const float* W_ih   = (const float*)d_in[4];
    const float* W_hh   = (const float*)d_in[5];
    const float* b_ih   = (const float*)d_in[6];
    const float* b_hh   = (const float*)d_in[7];
    float* out = (float*)d_out;
    (void)d_ws; (void)ws_size; (void)in_sizes; (void)n_in; (void)out_size;

    pack_attn<<<256, 256, 0, stream>>>(W_attn);
    pack_wih<<<2048, 256, 0, stream>>>(W_ih);
    pack_whh<<<1024, 256, 0, stream>>>(W_hh);
    pack_bias<<<4, 256, 0, stream>>>(b_ih, b_hh);
    mem_proj_gemm<<<dim3(1024, 4), 256, 0, stream>>>(memory, b_attn);
    emb_gemm<<<dim3(512, 16), 256, 0, stream>>>(tgt);
    decode_scan<<<128, 1024, 0, stream>>>(memory, out);
}